// Round 13
// baseline (339.437 us; speedup 1.0000x reference)
//
#include <hip/hip_runtime.h>
#include <hip/hip_fp16.h>

#define DCH 64
#define NBSHIFT 8
#define BROWS 256            // nodes per bucket = 1<<NBSHIFT
#define MAXNB 512
#define CAPB 5120            // fixed bucket capacity (mean 4092, +16 sigma)
#define CAP 8192             // pass-C LDS staging capacity
#define CHUNK 2048           // scatter edges per block (782 blocks: ~3/CU)

__global__ void init_cursor(int* __restrict__ cursor, int NB) {
    int i = blockIdx.x * blockDim.x + threadIdx.x;
    if (i < NB) cursor[i] = i * CAPB;
}

// single-pass scatter: per-chunk LDS hist -> global cursor reservation ->
// packed (dstLow8<<24)|src writes clustered per (chunk,bucket)
__global__ __launch_bounds__(256) void bucket_scatter(const int* __restrict__ src,
        const int* __restrict__ dst, int* __restrict__ cursor,
        unsigned int* __restrict__ tmp, int E, int NB) {
    __shared__ int hist[MAXNB];
    __shared__ int res[MAXNB];
    const int base_e = blockIdx.x * CHUNK;
    const int nloc = min(CHUNK, E - base_e);
    for (int i = threadIdx.x; i < NB; i += blockDim.x) hist[i] = 0;
    __syncthreads();
    for (int i = threadIdx.x; i < nloc; i += blockDim.x)
        atomicAdd(&hist[dst[base_e + i] >> NBSHIFT], 1);
    __syncthreads();
    for (int i = threadIdx.x; i < NB; i += blockDim.x) {
        int c = hist[i];
        res[i] = c ? atomicAdd(&cursor[i], c) : 0;
        hist[i] = 0;                       // reuse as local cursor
    }
    __syncthreads();
    for (int i = threadIdx.x; i < nloc; i += blockDim.x) {
        int d = dst[base_e + i];
        int b = d >> NBSHIFT;
        int r = atomicAdd(&hist[b], 1);
        unsigned int packed = ((unsigned int)(d & (BROWS - 1)) << 24) |
                              (unsigned int)src[base_e + i];
        tmp[res[b] + r] = packed;
    }
}

// one block per bucket -> rowbeg/rowend, dinv, coalesced (padded) srcs
__global__ __launch_bounds__(BROWS) void bucket_to_csr(
        const unsigned int* __restrict__ tmp, const int* __restrict__ cursor,
        int* __restrict__ rowbeg, int* __restrict__ rowend,
        int* __restrict__ srcs, float* __restrict__ dinv, int N) {
    __shared__ int hist[BROWS];
    __shared__ int off[BROWS];
    __shared__ int cur[BROWS];
    __shared__ int stage[CAP];
    const int b = blockIdx.x;
    const int base = b * CAPB;
    const int count = cursor[b] - base;
    const int t = threadIdx.x;
    hist[t] = 0;
    __syncthreads();
    for (int i = t; i < count; i += BROWS)
        atomicAdd(&hist[tmp[base + i] >> 24], 1);
    __syncthreads();
    int v = hist[t];
    off[t] = v;
    __syncthreads();
    for (int o = 1; o < BROWS; o <<= 1) {
        int add = (t >= o) ? off[t - o] : 0;
        __syncthreads();
        off[t] += add;
        __syncthreads();
    }
    int excl = off[t] - v;
    cur[t] = excl;
    int node = (b << NBSHIFT) + t;
    if (node < N) {
        rowbeg[node] = base + excl;
        rowend[node] = base + excl + v;
        dinv[node]   = rsqrtf((float)v + 1.0f);
    }
    __syncthreads();
    const bool st = (count <= CAP);
    for (int i = t; i < count; i += BROWS) {
        unsigned int p = tmp[base + i];
        int low = p >> 24;
        int s = (int)(p & 0xFFFFFFu);
        int pos = atomicAdd(&cur[low], 1);
        if (st) stage[pos] = s;
        else    srcs[base + pos] = s;
    }
    __syncthreads();
    if (st)
        for (int i = t; i < count; i += BROWS) srcs[base + i] = stage[i];
}

// register-tiled Hs[r][c] = half( (x*W1) * dinv[r] ); fp32 input, fp16 out
__global__ __launch_bounds__(256, 4) void gemm64(const float* __restrict__ A,
        const float* __restrict__ W, const float* __restrict__ dinv,
        __half* __restrict__ H, int nrows) {
    __shared__ float Wl[64 * 64];      // [k][c]
    __shared__ float Al[64 * 68];      // [r][k], pad 68
    #pragma unroll
    for (int j = 0; j < 4; ++j) {
        int idx = (int)threadIdx.x + j * 256;
        float4 w = ((const float4*)W)[idx];
        int k = idx >> 4, c = (idx & 15) * 4;
        *(float4*)&Wl[k * 64 + c] = w;
    }
    const int tx = threadIdx.x & 15;
    const int ty = threadIdx.x >> 4;
    const int c0 = tx * 4, r0 = ty * 4;
    const int ntiles = (nrows + 63) >> 6;
    for (int tile = blockIdx.x; tile < ntiles; tile += gridDim.x) {
        const int rowbase = tile << 6;
        const int rmax = min(64, nrows - rowbase);
        __syncthreads();
        #pragma unroll
        for (int j = 0; j < 4; ++j) {
            int idx = (int)threadIdx.x + j * 256;
            int r = idx >> 4, kq = idx & 15;
            float4 a = (r < rmax) ? *(const float4*)(A + (size_t)(rowbase + r) * 64 + kq * 4)
                                  : make_float4(0.f, 0.f, 0.f, 0.f);
            *(float4*)&Al[r * 68 + kq * 4] = a;
        }
        __syncthreads();
        float acc[4][4] = {};
        #pragma unroll 8
        for (int k = 0; k < 64; ++k) {
            float4 wv = *(const float4*)&Wl[k * 64 + c0];
            float a0 = Al[(r0 + 0) * 68 + k];
            float a1 = Al[(r0 + 1) * 68 + k];
            float a2 = Al[(r0 + 2) * 68 + k];
            float a3 = Al[(r0 + 3) * 68 + k];
            acc[0][0] += a0 * wv.x; acc[0][1] += a0 * wv.y; acc[0][2] += a0 * wv.z; acc[0][3] += a0 * wv.w;
            acc[1][0] += a1 * wv.x; acc[1][1] += a1 * wv.y; acc[1][2] += a1 * wv.z; acc[1][3] += a1 * wv.w;
            acc[2][0] += a2 * wv.x; acc[2][1] += a2 * wv.y; acc[2][2] += a2 * wv.z; acc[2][3] += a2 * wv.w;
            acc[3][0] += a3 * wv.x; acc[3][1] += a3 * wv.y; acc[3][2] += a3 * wv.z; acc[3][3] += a3 * wv.w;
        }
        #pragma unroll
        for (int i = 0; i < 4; ++i) {
            int r = r0 + i;
            if (r < rmax) {
                float s = dinv[rowbase + r];
                __half2* ph = (__half2*)(H + (size_t)(rowbase + r) * 64 + c0);
                ph[0] = __floats2half2_rn(acc[i][0] * s, acc[i][1] * s);
                ph[1] = __floats2half2_rn(acc[i][2] * s, acc[i][3] * s);
            }
        }
    }
}

__device__ __forceinline__ void accumh(__half2 acc[4], float4 v) {
    const __half2* hp = (const __half2*)&v;
    #pragma unroll
    for (int j = 0; j < 4; ++j) acc[j] = __hadd2(acc[j], hp[j]);
}

__device__ __forceinline__ float4 row16(const __half* __restrict__ hs, int s, int q) {
    return *(const float4*)((const char*)hs + ((size_t)s << 7) + (q << 4));
}

__device__ __forceinline__ float4 maskf4(float4 v, bool p) {
    return make_float4(p ? v.x : 0.f, p ? v.y : 0.f, p ? v.z : 0.f, p ? v.w : 0.f);
}

// quad-load gather + full xor-reduce. On return every lane holds
// acc[j] = sum_row[(lane&7)*8 + j] (pre-dinv, pre-bias).
__device__ __forceinline__ void gather_reduce(
    const __half* __restrict__ hs, const int* __restrict__ srcs,
    int beg, int end, int g, int q, int wid, float acc[8])
{
    __half2 z = __float2half2_rn(0.f);
    __half2 A[4] = {z,z,z,z}, B[4] = {z,z,z,z}, C[4] = {z,z,z,z}, D[4] = {z,z,z,z};
    if (g == 7) accumh(A, row16(hs, wid, q));       // self-loop on tail group
    for (int e = beg + g; e < end; e += 32) {       // 4 gathers in flight
        int last = end - 1;
        int i1 = min(e + 8,  last);
        int i2 = min(e + 16, last);
        int i3 = min(e + 24, last);
        int s0 = srcs[e], s1 = srcs[i1], s2 = srcs[i2], s3 = srcs[i3];
        float4 v0 = row16(hs, s0, q);
        float4 v1 = row16(hs, s1, q);
        float4 v2 = row16(hs, s2, q);
        float4 v3 = row16(hs, s3, q);
        accumh(A, v0);
        accumh(B, maskf4(v1, e + 8  < end));
        accumh(C, maskf4(v2, e + 16 < end));
        accumh(D, maskf4(v3, e + 24 < end));
    }
    #pragma unroll
    for (int j = 0; j < 4; ++j) {
        __half2 s = __hadd2(__hadd2(A[j], B[j]), __hadd2(C[j], D[j]));
        float2 f = __half22float2(s);
        acc[2 * j]     = f.x;
        acc[2 * j + 1] = f.y;
    }
    #pragma unroll
    for (int j = 0; j < 8; ++j) {
        float a = acc[j];
        a += __shfl_xor(a, 8);
        a += __shfl_xor(a, 16);
        a += __shfl_xor(a, 32);
        acc[j] = a;
    }
}

// fused aggregate + next-layer GEMM:
// row = relu( gather_sum * dinv[d] + bia );  hnext[d] = half( (row . Wn) * dinv[d] )
__global__ __launch_bounds__(512, 8) void agg_fused(
    const __half* __restrict__ hs, const int* __restrict__ rowbeg,
    const int* __restrict__ rowend, const int* __restrict__ srcs,
    const float* __restrict__ dinv, const float* __restrict__ bia,
    const float* __restrict__ Wn, __half* __restrict__ hnext, int n)
{
    __shared__ __half Wt[64][68];      // transposed Wn, fp16, pad 68 (4B-aligned rows)
    for (int i = threadIdx.x; i < 4096; i += 512) {
        int k = i >> 6, c = i & 63;
        Wt[c][k] = __float2half(Wn[i]);
    }
    __syncthreads();
    int wid = (int)((blockIdx.x * 512 + threadIdx.x) >> 6);   // 8 nodes/block
    if (wid >= n) return;
    int lane = threadIdx.x & 63;
    int g = lane >> 3, q = lane & 7;
    float acc[8];
    gather_reduce(hs, srcs, rowbeg[wid], rowend[wid], g, q, wid, acc);
    float dd = dinv[wid];
    float v[8];
    #pragma unroll
    for (int j = 0; j < 8; ++j)
        v[j] = fmaxf(acc[j] * dd + bia[q * 8 + j], 0.f);
    // row . Wn : lane -> output channel. row[ko*8+j] = shfl(v[j], ko).
    float o = 0.f;
    #pragma unroll
    for (int ko = 0; ko < 8; ++ko) {
        #pragma unroll
        for (int j = 0; j < 8; j += 2) {
            float r0 = __shfl(v[j],     ko);
            float r1 = __shfl(v[j + 1], ko);
            __half2 w2 = *(const __half2*)&Wt[lane][ko * 8 + j];
            float2 wf = __half22float2(w2);
            o += r0 * wf.x + r1 * wf.y;
        }
    }
    hnext[(size_t)wid * DCH + lane] = __float2half(o * dd);
}

// final aggregate: fp32 output, bias, no relu
__global__ __launch_bounds__(256) void agg_final(
    const __half* __restrict__ hs, const int* __restrict__ rowbeg,
    const int* __restrict__ rowend, const int* __restrict__ srcs,
    const float* __restrict__ dinv, const float* __restrict__ b,
    float* __restrict__ out, int n)
{
    int wid  = (blockIdx.x * blockDim.x + threadIdx.x) >> 6;
    if (wid >= n) return;
    int lane = threadIdx.x & 63;
    int g = lane >> 3, q = lane & 7;
    float acc[8];
    gather_reduce(hs, srcs, rowbeg[wid], rowend[wid], g, q, wid, acc);
    if (g == 0) {
        float dd = dinv[wid];
        float o[8];
        #pragma unroll
        for (int j = 0; j < 8; ++j) o[j] = acc[j] * dd + b[q * 8 + j];
        float4* po = (float4*)(out + (size_t)wid * DCH + q * 8);
        po[0] = make_float4(o[0], o[1], o[2], o[3]);
        po[1] = make_float4(o[4], o[5], o[6], o[7]);
    }
}

extern "C" void kernel_launch(void* const* d_in, const int* in_sizes, int n_in,
                              void* d_out, int out_size, void* d_ws, size_t ws_size,
                              hipStream_t stream) {
    const float* x  = (const float*)d_in[0];
    const int*   ei = (const int*)d_in[1];
    const float* W1 = (const float*)d_in[2];
    const float* b1 = (const float*)d_in[3];
    const float* W2 = (const float*)d_in[4];
    const float* b2 = (const float*)d_in[5];
    const float* W3 = (const float*)d_in[6];
    const float* b3 = (const float*)d_in[7];

    const int N = in_sizes[0] / DCH;
    const int E = in_sizes[1] / 2;
    const int* src = ei;
    const int* dst = ei + E;
    const int NB = (N + BROWS - 1) >> NBSHIFT;     // 391

    char* ws = (char*)d_ws;
    size_t off = 0;
    auto alloc = [&](size_t bytes) { void* p = ws + off; off = (off + bytes + 255) & ~(size_t)255; return p; };
    int*    cursor = (int*)   alloc((size_t)MAXNB * 4);
    int*    rowbeg = (int*)   alloc((size_t)N * 4);
    int*    rowend = (int*)   alloc((size_t)N * 4);
    int*    srcs   = (int*)   alloc((size_t)NB * CAPB * 4);   // padded CSR
    float*  dinv   = (float*) alloc((size_t)N * 4);
    __half* hs1    = (__half*)alloc((size_t)N * DCH * 2);
    __half* hs2    = (__half*)alloc((size_t)N * DCH * 2);
    unsigned int* tmp = (unsigned int*)hs1;        // alias: dead before gemm1 writes hs1
    float* out = (float*)d_out;

    const int T = 256;
    const int gAGf = (N + 7) / 8;                  // agg_fused: 512 thr, 8 nodes/block
    const int gAGl = (N * DCH + T - 1) / T;        // agg_final: 1 wave/node
    const int gGM  = (N + 63) / 64;
    const int nchk = (E + CHUNK - 1) / CHUNK;

    // ---- CSR build (counting sort by dst, fixed-capacity buckets) ----
    init_cursor<<<(NB + T - 1) / T, T, 0, stream>>>(cursor, NB);
    bucket_scatter<<<nchk, T, 0, stream>>>(src, dst, cursor, tmp, E, NB);
    bucket_to_csr<<<NB, BROWS, 0, stream>>>(tmp, cursor, rowbeg, rowend, srcs, dinv, N);

    // ---- layer 1 GEMM: x -> hs1 (fp16, pre-scaled) ----
    gemm64<<<gGM, T, 0, stream>>>(x, W1, dinv, hs1, N);

    // ---- layer 1 agg + layer 2 GEMM fused: hs1 -> hs2 ----
    agg_fused<<<gAGf, 512, 0, stream>>>(hs1, rowbeg, rowend, srcs, dinv, b1, W2, hs2, N);

    // ---- layer 2 agg + layer 3 GEMM fused: hs2 -> hs1 ----
    agg_fused<<<gAGf, 512, 0, stream>>>(hs2, rowbeg, rowend, srcs, dinv, b2, W3, hs1, N);

    // ---- layer 3 agg: hs1 -> d_out (fp32) ----
    agg_final<<<gAGl, T, 0, stream>>>(hs1, rowbeg, rowend, srcs, dinv, b3, out, N);
}

// Round 14
// 281.503 us; speedup vs baseline: 1.2058x; 1.2058x over previous
//
#include <hip/hip_runtime.h>
#include <hip/hip_fp16.h>

#define DCH 64
#define NBSHIFT 8
#define BROWS 256            // nodes per bucket = 1<<NBSHIFT
#define MAXNB 512
#define CAPB 5120            // fixed bucket capacity (mean 4092, +16 sigma)
#define CAP 8192             // pass-C LDS staging capacity
#define CHUNK 4096           // scatter edges per block

// single-pass scatter: per-chunk LDS hist -> global cursor reservation ->
// packed (dstLow8<<24)|src writes clustered per (chunk,bucket).
// cursor starts zeroed (relative); tmp slot = b*CAPB + rel.
__global__ __launch_bounds__(256) void bucket_scatter(const int* __restrict__ src,
        const int* __restrict__ dst, int* __restrict__ cursor,
        unsigned int* __restrict__ tmp, int E, int NB) {
    __shared__ int hist[MAXNB];
    __shared__ int res[MAXNB];
    const int base_e = blockIdx.x * CHUNK;
    const int nloc = min(CHUNK, E - base_e);
    for (int i = threadIdx.x; i < NB; i += blockDim.x) hist[i] = 0;
    __syncthreads();
    for (int i = threadIdx.x; i < nloc; i += blockDim.x)
        atomicAdd(&hist[dst[base_e + i] >> NBSHIFT], 1);
    __syncthreads();
    for (int i = threadIdx.x; i < NB; i += blockDim.x) {
        int c = hist[i];
        res[i] = c ? (i * CAPB + atomicAdd(&cursor[i], c)) : 0;
        hist[i] = 0;                       // reuse as local cursor
    }
    __syncthreads();
    for (int i = threadIdx.x; i < nloc; i += blockDim.x) {
        int d = dst[base_e + i];
        int b = d >> NBSHIFT;
        int r = atomicAdd(&hist[b], 1);
        unsigned int packed = ((unsigned int)(d & (BROWS - 1)) << 24) |
                              (unsigned int)src[base_e + i];
        tmp[res[b] + r] = packed;
    }
}

// one block per bucket -> rowbeg/rowend, dinv, coalesced (padded) srcs
__global__ __launch_bounds__(BROWS) void bucket_to_csr(
        const unsigned int* __restrict__ tmp, const int* __restrict__ cursor,
        int* __restrict__ rowbeg, int* __restrict__ rowend,
        int* __restrict__ srcs, float* __restrict__ dinv, int N) {
    __shared__ int hist[BROWS];
    __shared__ int off[BROWS];
    __shared__ int cur[BROWS];
    __shared__ int stage[CAP];
    const int b = blockIdx.x;
    const int base = b * CAPB;
    const int count = cursor[b];
    const int t = threadIdx.x;
    hist[t] = 0;
    __syncthreads();
    for (int i = t; i < count; i += BROWS)
        atomicAdd(&hist[tmp[base + i] >> 24], 1);
    __syncthreads();
    int v = hist[t];
    off[t] = v;
    __syncthreads();
    for (int o = 1; o < BROWS; o <<= 1) {
        int add = (t >= o) ? off[t - o] : 0;
        __syncthreads();
        off[t] += add;
        __syncthreads();
    }
    int excl = off[t] - v;
    cur[t] = excl;
    int node = (b << NBSHIFT) + t;
    if (node < N) {
        rowbeg[node] = base + excl;
        rowend[node] = base + excl + v;
        dinv[node]   = rsqrtf((float)v + 1.0f);
    }
    __syncthreads();
    const bool st = (count <= CAP);
    for (int i = t; i < count; i += BROWS) {
        unsigned int p = tmp[base + i];
        int low = p >> 24;
        int s = (int)(p & 0xFFFFFFu);
        int pos = atomicAdd(&cur[low], 1);
        if (st) stage[pos] = s;
        else    srcs[base + pos] = s;
    }
    __syncthreads();
    if (st)
        for (int i = t; i < count; i += BROWS) srcs[base + i] = stage[i];
}

// register-tiled Hs[r][c] = half( (x*W1) * dinv[r] ); fp32 input, fp16 out
__global__ __launch_bounds__(256, 4) void gemm64(const float* __restrict__ A,
        const float* __restrict__ W, const float* __restrict__ dinv,
        __half* __restrict__ H, int nrows) {
    __shared__ float Wl[64 * 64];      // [k][c]
    __shared__ float Al[64 * 68];      // [r][k], pad 68
    #pragma unroll
    for (int j = 0; j < 4; ++j) {
        int idx = (int)threadIdx.x + j * 256;
        float4 w = ((const float4*)W)[idx];
        *(float4*)&Wl[(idx >> 4) * 64 + (idx & 15) * 4] = w;
    }
    const int tx = threadIdx.x & 15;
    const int ty = threadIdx.x >> 4;
    const int c0 = tx * 4, r0 = ty * 4;
    const int ntiles = (nrows + 63) >> 6;
    for (int tile = blockIdx.x; tile < ntiles; tile += gridDim.x) {
        const int rowbase = tile << 6;
        const int rmax = min(64, nrows - rowbase);
        __syncthreads();
        #pragma unroll
        for (int j = 0; j < 4; ++j) {
            int idx = (int)threadIdx.x + j * 256;
            int r = idx >> 4, kq = idx & 15;
            float4 a = (r < rmax) ? *(const float4*)(A + (size_t)(rowbase + r) * 64 + kq * 4)
                                  : make_float4(0.f, 0.f, 0.f, 0.f);
            *(float4*)&Al[r * 68 + kq * 4] = a;
        }
        __syncthreads();
        float acc[4][4] = {};
        #pragma unroll 8
        for (int k = 0; k < 64; ++k) {
            float4 wv = *(const float4*)&Wl[k * 64 + c0];
            float a0 = Al[(r0 + 0) * 68 + k];
            float a1 = Al[(r0 + 1) * 68 + k];
            float a2 = Al[(r0 + 2) * 68 + k];
            float a3 = Al[(r0 + 3) * 68 + k];
            acc[0][0] += a0 * wv.x; acc[0][1] += a0 * wv.y; acc[0][2] += a0 * wv.z; acc[0][3] += a0 * wv.w;
            acc[1][0] += a1 * wv.x; acc[1][1] += a1 * wv.y; acc[1][2] += a1 * wv.z; acc[1][3] += a1 * wv.w;
            acc[2][0] += a2 * wv.x; acc[2][1] += a2 * wv.y; acc[2][2] += a2 * wv.z; acc[2][3] += a2 * wv.w;
            acc[3][0] += a3 * wv.x; acc[3][1] += a3 * wv.y; acc[3][2] += a3 * wv.z; acc[3][3] += a3 * wv.w;
        }
        #pragma unroll
        for (int i = 0; i < 4; ++i) {
            int r = r0 + i;
            if (r < rmax) {
                float s = dinv[rowbase + r];
                __half2* ph = (__half2*)(H + (size_t)(rowbase + r) * 64 + c0);
                ph[0] = __floats2half2_rn(acc[i][0] * s, acc[i][1] * s);
                ph[1] = __floats2half2_rn(acc[i][2] * s, acc[i][3] * s);
            }
        }
    }
}

__device__ __forceinline__ void accumh(__half2 acc[4], float4 v) {
    const __half2* hp = (const __half2*)&v;
    #pragma unroll
    for (int j = 0; j < 4; ++j) acc[j] = __hadd2(acc[j], hp[j]);
}

__device__ __forceinline__ float4 row16(const __half* __restrict__ hs, int s, int q) {
    return *(const float4*)((const char*)hs + ((size_t)s << 7) + (q << 4));
}

// block-level fused layer: 128 nodes/block (512 thr, 8 waves).
// phase 1: per-wave R12 gather (dual-load, fp16 accum) -> relu'd fp32 row in Al.
// phase 2: proven register-tiled GEMM from Al -> hnext fp16 pre-scaled by dinv.
__global__ __launch_bounds__(512, 6) void fused_layer(
    const __half* __restrict__ hs, const int* __restrict__ rowbeg,
    const int* __restrict__ rowend, const int* __restrict__ srcs,
    const float* __restrict__ dinv, const float* __restrict__ bia,
    const float* __restrict__ W, __half* __restrict__ hnext, int n)
{
    __shared__ float Wl[64 * 64];      // [k][c], fp32
    __shared__ float Al[128 * 68];     // [r][k], pad 68
    #pragma unroll
    for (int j = 0; j < 2; ++j) {
        int idx = (int)threadIdx.x + j * 512;
        float4 w = ((const float4*)W)[idx];
        *(float4*)&Wl[(idx >> 4) * 64 + (idx & 15) * 4] = w;
    }
    const int rowbase = blockIdx.x << 7;
    const int wv   = threadIdx.x >> 6;     // wave 0..7
    const int lane = threadIdx.x & 63;
    const int g = lane >> 3, q = lane & 7;
    float bv[8];
    #pragma unroll
    for (int j = 0; j < 8; ++j) bv[j] = bia[q * 8 + j];

    for (int rep = 0; rep < 16; ++rep) {
        const int r = rep * 8 + wv;
        const int wid = rowbase + r;
        const bool valid = wid < n;        // wave-uniform
        float acc[8];
        if (valid) {
            int beg = rowbeg[wid], end = rowend[wid];
            __half2 zero = __float2half2_rn(0.f);
            __half2 acch[4]  = {zero, zero, zero, zero};
            __half2 acch2[4] = {zero, zero, zero, zero};
            if (g == 7) accumh(acch, row16(hs, wid, q));   // self-loop
            int e = beg + g;
            for (; e + 8 < end; e += 16) {                 // 2 gathers in flight
                int s0 = srcs[e];
                int s1 = srcs[e + 8];
                float4 v0 = row16(hs, s0, q);
                float4 v1 = row16(hs, s1, q);
                accumh(acch, v0);
                accumh(acch2, v1);
            }
            if (e < end) accumh(acch, row16(hs, srcs[e], q));
            #pragma unroll
            for (int j = 0; j < 4; ++j) {
                float2 f0 = __half22float2(acch[j]);
                float2 f1 = __half22float2(acch2[j]);
                acc[2 * j]     = f0.x + f1.x;
                acc[2 * j + 1] = f0.y + f1.y;
            }
            #pragma unroll
            for (int j = 0; j < 8; ++j) {
                float a = acc[j];
                a += __shfl_xor(a, 8);
                a += __shfl_xor(a, 16);
                a += __shfl_xor(a, 32);
                acc[j] = a;
            }
        }
        if (g == 0) {
            float4 o0 = make_float4(0.f, 0.f, 0.f, 0.f), o1 = o0;
            if (valid) {
                float dd = dinv[wid];
                o0.x = fmaxf(acc[0] * dd + bv[0], 0.f);
                o0.y = fmaxf(acc[1] * dd + bv[1], 0.f);
                o0.z = fmaxf(acc[2] * dd + bv[2], 0.f);
                o0.w = fmaxf(acc[3] * dd + bv[3], 0.f);
                o1.x = fmaxf(acc[4] * dd + bv[4], 0.f);
                o1.y = fmaxf(acc[5] * dd + bv[5], 0.f);
                o1.z = fmaxf(acc[6] * dd + bv[6], 0.f);
                o1.w = fmaxf(acc[7] * dd + bv[7], 0.f);
            }
            *(float4*)&Al[r * 68 + q * 8]     = o0;
            *(float4*)&Al[r * 68 + q * 8 + 4] = o1;
        }
    }
    __syncthreads();
    // phase 2: [128x64] = Al * Wl
    const int tx = threadIdx.x & 15;
    const int ty = threadIdx.x >> 4;       // 0..31
    const int c0 = tx * 4, r0 = ty * 4;
    float acc2[4][4] = {};
    #pragma unroll 8
    for (int k = 0; k < 64; ++k) {
        float4 wv4 = *(const float4*)&Wl[k * 64 + c0];
        float a0 = Al[(r0 + 0) * 68 + k];
        float a1 = Al[(r0 + 1) * 68 + k];
        float a2 = Al[(r0 + 2) * 68 + k];
        float a3 = Al[(r0 + 3) * 68 + k];
        acc2[0][0] += a0 * wv4.x; acc2[0][1] += a0 * wv4.y; acc2[0][2] += a0 * wv4.z; acc2[0][3] += a0 * wv4.w;
        acc2[1][0] += a1 * wv4.x; acc2[1][1] += a1 * wv4.y; acc2[1][2] += a1 * wv4.z; acc2[1][3] += a1 * wv4.w;
        acc2[2][0] += a2 * wv4.x; acc2[2][1] += a2 * wv4.y; acc2[2][2] += a2 * wv4.z; acc2[2][3] += a2 * wv4.w;
        acc2[3][0] += a3 * wv4.x; acc2[3][1] += a3 * wv4.y; acc2[3][2] += a3 * wv4.z; acc2[3][3] += a3 * wv4.w;
    }
    const int rmax = min(128, n - rowbase);
    #pragma unroll
    for (int i = 0; i < 4; ++i) {
        int r = r0 + i;
        if (r < rmax) {
            float s = dinv[rowbase + r];
            __half2* ph = (__half2*)(hnext + (size_t)(rowbase + r) * 64 + c0);
            ph[0] = __floats2half2_rn(acc2[i][0] * s, acc2[i][1] * s);
            ph[1] = __floats2half2_rn(acc2[i][2] * s, acc2[i][3] * s);
        }
    }
}

// final aggregate: fp32 output, bias, no relu (R12 champion structure)
__global__ __launch_bounds__(256) void agg_final(
    const __half* __restrict__ hs, const int* __restrict__ rowbeg,
    const int* __restrict__ rowend, const int* __restrict__ srcs,
    const float* __restrict__ dinv, const float* __restrict__ b,
    float* __restrict__ out, int n)
{
    int wid  = (blockIdx.x * blockDim.x + threadIdx.x) >> 6;
    if (wid >= n) return;
    int lane = threadIdx.x & 63;
    const int g = lane >> 3, q = lane & 7;
    int beg = rowbeg[wid], end = rowend[wid];
    __half2 zero = __float2half2_rn(0.f);
    __half2 acch[4]  = {zero, zero, zero, zero};
    __half2 acch2[4] = {zero, zero, zero, zero};
    if (g == 7) accumh(acch, row16(hs, wid, q));
    int e = beg + g;
    for (; e + 8 < end; e += 16) {
        int s0 = srcs[e];
        int s1 = srcs[e + 8];
        float4 v0 = row16(hs, s0, q);
        float4 v1 = row16(hs, s1, q);
        accumh(acch, v0);
        accumh(acch2, v1);
    }
    if (e < end) accumh(acch, row16(hs, srcs[e], q));
    float acc[8];
    #pragma unroll
    for (int j = 0; j < 4; ++j) {
        float2 f0 = __half22float2(acch[j]);
        float2 f1 = __half22float2(acch2[j]);
        acc[2 * j]     = f0.x + f1.x;
        acc[2 * j + 1] = f0.y + f1.y;
    }
    #pragma unroll
    for (int j = 0; j < 8; ++j) {
        float a = acc[j];
        a += __shfl_xor(a, 8);
        a += __shfl_xor(a, 16);
        a += __shfl_xor(a, 32);
        acc[j] = a;
    }
    if (g == 0) {
        float dd = dinv[wid];
        float o[8];
        #pragma unroll
        for (int j = 0; j < 8; ++j) o[j] = acc[j] * dd + b[q * 8 + j];
        float4* po = (float4*)(out + (size_t)wid * DCH + q * 8);
        po[0] = make_float4(o[0], o[1], o[2], o[3]);
        po[1] = make_float4(o[4], o[5], o[6], o[7]);
    }
}

extern "C" void kernel_launch(void* const* d_in, const int* in_sizes, int n_in,
                              void* d_out, int out_size, void* d_ws, size_t ws_size,
                              hipStream_t stream) {
    const float* x  = (const float*)d_in[0];
    const int*   ei = (const int*)d_in[1];
    const float* W1 = (const float*)d_in[2];
    const float* b1 = (const float*)d_in[3];
    const float* W2 = (const float*)d_in[4];
    const float* b2 = (const float*)d_in[5];
    const float* W3 = (const float*)d_in[6];
    const float* b3 = (const float*)d_in[7];

    const int N = in_sizes[0] / DCH;
    const int E = in_sizes[1] / 2;
    const int* src = ei;
    const int* dst = ei + E;
    const int NB = (N + BROWS - 1) >> NBSHIFT;     // 391

    char* ws = (char*)d_ws;
    size_t off = 0;
    auto alloc = [&](size_t bytes) { void* p = ws + off; off = (off + bytes + 255) & ~(size_t)255; return p; };
    int*    cursor = (int*)   alloc((size_t)MAXNB * 4);
    int*    rowbeg = (int*)   alloc((size_t)N * 4);
    int*    rowend = (int*)   alloc((size_t)N * 4);
    int*    srcs   = (int*)   alloc((size_t)NB * CAPB * 4);   // padded CSR
    float*  dinv   = (float*) alloc((size_t)N * 4);
    __half* hs1    = (__half*)alloc((size_t)N * DCH * 2);
    __half* hs2    = (__half*)alloc((size_t)N * DCH * 2);
    unsigned int* tmp = (unsigned int*)hs1;        // alias: 8MB tmp < 12.8MB hs1; dead before gemm1
    float* out = (float*)d_out;

    const int T = 256;
    const int gAGl = (N * DCH + T - 1) / T;        // agg_final: 1 wave/node
    const int gFU  = (N + 127) / 128;              // fused: 128 nodes/block
    const int gGM  = (N + 63) / 64;
    const int nchk = (E + CHUNK - 1) / CHUNK;

    // ---- CSR build (counting sort by dst, fixed-capacity buckets) ----
    hipMemsetAsync(cursor, 0, (size_t)NB * 4, stream);
    bucket_scatter<<<nchk, T, 0, stream>>>(src, dst, cursor, tmp, E, NB);
    bucket_to_csr<<<NB, BROWS, 0, stream>>>(tmp, cursor, rowbeg, rowend, srcs, dinv, N);

    // ---- layer 1 GEMM: x -> hs1 (fp16, pre-scaled) ----
    gemm64<<<gGM, T, 0, stream>>>(x, W1, dinv, hs1, N);

    // ---- layer 1 agg + layer 2 GEMM (block-fused): hs1 -> hs2 ----
    fused_layer<<<gFU, 512, 0, stream>>>(hs1, rowbeg, rowend, srcs, dinv, b1, W2, hs2, N);

    // ---- layer 2 agg + layer 3 GEMM (block-fused): hs2 -> hs1 ----
    fused_layer<<<gFU, 512, 0, stream>>>(hs2, rowbeg, rowend, srcs, dinv, b2, W3, hs1, N);

    // ---- layer 3 agg: hs1 -> d_out (fp32) ----
    agg_final<<<gAGl, T, 0, stream>>>(hs1, rowbeg, rowend, srcs, dinv, b3, out, N);
}

// Round 15
// 246.354 us; speedup vs baseline: 1.3778x; 1.1427x over previous
//
#include <hip/hip_runtime.h>
#include <hip/hip_fp16.h>
#include <type_traits>

#define DCH 64
#define NBSHIFT 7
#define BROWS 128            // nodes per bucket = 1<<NBSHIFT
#define MAXNB 1024
#define CAPB 2816            // fixed bucket capacity (mean 2048, +17 sigma)
#define CAP 4096             // pass-C LDS staging capacity (>= CAPB)
#define CHUNK 2048           // scatter edges per block (782 blocks)

// single-pass scatter: per-chunk LDS hist -> global cursor reservation ->
// packed (dstLow7<<24)|src writes clustered per (chunk,bucket).
// cursor starts zeroed (relative); tmp slot = b*CAPB + rel.
__global__ __launch_bounds__(256) void bucket_scatter(const int* __restrict__ src,
        const int* __restrict__ dst, int* __restrict__ cursor,
        unsigned int* __restrict__ tmp, int E, int NB) {
    __shared__ int hist[MAXNB];
    __shared__ int res[MAXNB];
    const int base_e = blockIdx.x * CHUNK;
    const int nloc = min(CHUNK, E - base_e);
    for (int i = threadIdx.x; i < NB; i += blockDim.x) hist[i] = 0;
    __syncthreads();
    for (int i = threadIdx.x; i < nloc; i += blockDim.x)
        atomicAdd(&hist[dst[base_e + i] >> NBSHIFT], 1);
    __syncthreads();
    for (int i = threadIdx.x; i < NB; i += blockDim.x) {
        int c = hist[i];
        res[i] = c ? (i * CAPB + atomicAdd(&cursor[i], c)) : 0;
        hist[i] = 0;                       // reuse as local cursor
    }
    __syncthreads();
    for (int i = threadIdx.x; i < nloc; i += blockDim.x) {
        int d = dst[base_e + i];
        int b = d >> NBSHIFT;
        int r = atomicAdd(&hist[b], 1);
        unsigned int packed = ((unsigned int)(d & (BROWS - 1)) << 24) |
                              (unsigned int)src[base_e + i];
        tmp[res[b] + r] = packed;
    }
}

// one block per bucket -> range(int2), dinv, coalesced (padded) srcs
__global__ __launch_bounds__(BROWS) void bucket_to_csr(
        const unsigned int* __restrict__ tmp, const int* __restrict__ cursor,
        int2* __restrict__ range, int* __restrict__ srcs,
        float* __restrict__ dinv, int N) {
    __shared__ int hist[BROWS];
    __shared__ int off[BROWS];
    __shared__ int cur[BROWS];
    __shared__ int stage[CAP];
    const int b = blockIdx.x;
    const int base = b * CAPB;
    const int count = cursor[b];
    const int t = threadIdx.x;
    hist[t] = 0;
    __syncthreads();
    for (int i = t; i < count; i += BROWS)
        atomicAdd(&hist[tmp[base + i] >> 24], 1);
    __syncthreads();
    int v = hist[t];
    off[t] = v;
    __syncthreads();
    for (int o = 1; o < BROWS; o <<= 1) {
        int add = (t >= o) ? off[t - o] : 0;
        __syncthreads();
        off[t] += add;
        __syncthreads();
    }
    int excl = off[t] - v;
    cur[t] = excl;
    int node = (b << NBSHIFT) + t;
    if (node < N) {
        range[node] = make_int2(base + excl, base + excl + v);
        dinv[node]  = rsqrtf((float)v + 1.0f);
    }
    __syncthreads();
    const bool st = (count <= CAP);
    for (int i = t; i < count; i += BROWS) {
        unsigned int p = tmp[base + i];
        int low = p >> 24;
        int s = (int)(p & 0xFFFFFFu);
        int pos = atomicAdd(&cur[low], 1);
        if (st) stage[pos] = s;
        else    srcs[base + pos] = s;
    }
    __syncthreads();
    if (st)
        for (int i = t; i < count; i += BROWS) srcs[base + i] = stage[i];
}

// register-tiled Hs[r][c] = half( (A*W) * dinv[r] ); 64x64 tile, 4x4/thread.
// InT = float or __half, both row-major [N][64].
template<typename InT>
__global__ __launch_bounds__(256, 4) void gemm64(const InT* __restrict__ A,
        const float* __restrict__ W, const float* __restrict__ dinv,
        __half* __restrict__ H, int nrows) {
    __shared__ float Wl[64 * 64];      // [k][c]
    __shared__ float Al[64 * 68];      // [r][k], pad 68
    #pragma unroll
    for (int j = 0; j < 4; ++j) {
        int idx = (int)threadIdx.x + j * 256;
        float4 w = ((const float4*)W)[idx];
        *(float4*)&Wl[(idx >> 4) * 64 + (idx & 15) * 4] = w;
    }
    const int tx = threadIdx.x & 15;
    const int ty = threadIdx.x >> 4;
    const int c0 = tx * 4, r0 = ty * 4;
    const int ntiles = (nrows + 63) >> 6;
    for (int tile = blockIdx.x; tile < ntiles; tile += gridDim.x) {
        const int rowbase = tile << 6;
        const int rmax = min(64, nrows - rowbase);
        __syncthreads();
        #pragma unroll
        for (int j = 0; j < 4; ++j) {
            int idx = (int)threadIdx.x + j * 256;
            int r = idx >> 4, kq = idx & 15;
            float4 a;
            if (r < rmax) {
                if constexpr (std::is_same<InT, float>::value) {
                    a = *(const float4*)(A + (size_t)(rowbase + r) * 64 + kq * 4);
                } else {
                    unsigned long long u = *(const unsigned long long*)
                        ((const __half*)A + (size_t)(rowbase + r) * 64 + kq * 4);
                    union { unsigned long long u; __half2 h[2]; } cv; cv.u = u;
                    float2 f0 = __half22float2(cv.h[0]);
                    float2 f1 = __half22float2(cv.h[1]);
                    a = make_float4(f0.x, f0.y, f1.x, f1.y);
                }
            } else a = make_float4(0.f, 0.f, 0.f, 0.f);
            *(float4*)&Al[r * 68 + kq * 4] = a;
        }
        __syncthreads();
        float acc[4][4] = {};
        #pragma unroll 8
        for (int k = 0; k < 64; ++k) {
            float4 wv = *(const float4*)&Wl[k * 64 + c0];
            float a0 = Al[(r0 + 0) * 68 + k];
            float a1 = Al[(r0 + 1) * 68 + k];
            float a2 = Al[(r0 + 2) * 68 + k];
            float a3 = Al[(r0 + 3) * 68 + k];
            acc[0][0] += a0 * wv.x; acc[0][1] += a0 * wv.y; acc[0][2] += a0 * wv.z; acc[0][3] += a0 * wv.w;
            acc[1][0] += a1 * wv.x; acc[1][1] += a1 * wv.y; acc[1][2] += a1 * wv.z; acc[1][3] += a1 * wv.w;
            acc[2][0] += a2 * wv.x; acc[2][1] += a2 * wv.y; acc[2][2] += a2 * wv.z; acc[2][3] += a2 * wv.w;
            acc[3][0] += a3 * wv.x; acc[3][1] += a3 * wv.y; acc[3][2] += a3 * wv.z; acc[3][3] += a3 * wv.w;
        }
        #pragma unroll
        for (int i = 0; i < 4; ++i) {
            int r = r0 + i;
            if (r < rmax) {
                float s = dinv[rowbase + r];
                __half2* ph = (__half2*)(H + (size_t)(rowbase + r) * 64 + c0);
                ph[0] = __floats2half2_rn(acc[i][0] * s, acc[i][1] * s);
                ph[1] = __floats2half2_rn(acc[i][2] * s, acc[i][3] * s);
            }
        }
    }
}

__device__ __forceinline__ void accumh(__half2 acc[4], float4 v) {
    const __half2* hp = (const __half2*)&v;
    #pragma unroll
    for (int j = 0; j < 4; ++j) acc[j] = __hadd2(acc[j], hp[j]);
}

__device__ __forceinline__ float4 row16(const __half* __restrict__ hs, int s, int q) {
    return *(const float4*)((const char*)hs + ((size_t)s << 7) + (q << 4));
}

// one wave per dst node (champion structure). lane = g*8+q: g = edge subgroup
// (8 edges/load-instr), q = channel oct (16B). fp16 packed accum, dual loads.
// OutT=__half: fp16 [N][64] inter-layer; OutT=float: fp32 d_out.
// out[d][c] = act( (sum_{s in N(d) ∪ {d}} hs[s][c]) * dinv[d] + b[c] )
template<typename OutT>
__global__ __launch_bounds__(256) void aggregate(
    const __half* __restrict__ hs, const int2* __restrict__ range,
    const int* __restrict__ srcs, const float* __restrict__ dinv,
    const float* __restrict__ b, OutT* __restrict__ out, int n, int do_relu)
{
    int wid  = (blockIdx.x * blockDim.x + threadIdx.x) >> 6;
    int lane = threadIdx.x & 63;
    if (wid >= n) return;
    const int g = lane >> 3;       // 0..7
    const int q = lane & 7;        // 0..7
    const int2 be = range[wid];
    const int beg = be.x, end = be.y;
    __half2 zero = __float2half2_rn(0.f);
    __half2 acch[4]  = {zero, zero, zero, zero};
    __half2 acch2[4] = {zero, zero, zero, zero};
    if (g == 7) accumh(acch, row16(hs, wid, q));    // self-loop on tail group
    int e = beg + g;
    for (; e + 8 < end; e += 16) {                  // 2 gathers in flight
        int s0 = srcs[e];
        int s1 = srcs[e + 8];
        float4 v0 = row16(hs, s0, q);
        float4 v1 = row16(hs, s1, q);
        accumh(acch, v0);
        accumh(acch2, v1);
    }
    if (e < end) accumh(acch, row16(hs, srcs[e], q));
    float acc[8];
    #pragma unroll
    for (int j = 0; j < 4; ++j) {
        float2 f0 = __half22float2(acch[j]);
        float2 f1 = __half22float2(acch2[j]);
        acc[2 * j]     = f0.x + f1.x;
        acc[2 * j + 1] = f0.y + f1.y;
    }
    #pragma unroll
    for (int j = 0; j < 8; ++j) {
        float a = acc[j];
        a += __shfl_xor(a, 8);
        a += __shfl_xor(a, 16);
        a += __shfl_xor(a, 32);
        acc[j] = a;
    }
    if (g == 0) {
        float dd = dinv[wid];
        float o[8];
        #pragma unroll
        for (int j = 0; j < 8; ++j) {
            float v = acc[j] * dd + b[q * 8 + j];
            o[j] = do_relu ? fmaxf(v, 0.f) : v;
        }
        if constexpr (std::is_same<OutT, __half>::value) {
            union { uint4 u; __half2 h[4]; } cv;
            cv.h[0] = __floats2half2_rn(o[0], o[1]);
            cv.h[1] = __floats2half2_rn(o[2], o[3]);
            cv.h[2] = __floats2half2_rn(o[4], o[5]);
            cv.h[3] = __floats2half2_rn(o[6], o[7]);
            *(uint4*)((__half*)out + (size_t)wid * DCH + q * 8) = cv.u;
        } else {
            float4* po = (float4*)((float*)out + (size_t)wid * DCH + q * 8);
            po[0] = make_float4(o[0], o[1], o[2], o[3]);
            po[1] = make_float4(o[4], o[5], o[6], o[7]);
        }
    }
}

extern "C" void kernel_launch(void* const* d_in, const int* in_sizes, int n_in,
                              void* d_out, int out_size, void* d_ws, size_t ws_size,
                              hipStream_t stream) {
    const float* x  = (const float*)d_in[0];
    const int*   ei = (const int*)d_in[1];
    const float* W1 = (const float*)d_in[2];
    const float* b1 = (const float*)d_in[3];
    const float* W2 = (const float*)d_in[4];
    const float* b2 = (const float*)d_in[5];
    const float* W3 = (const float*)d_in[6];
    const float* b3 = (const float*)d_in[7];

    const int N = in_sizes[0] / DCH;
    const int E = in_sizes[1] / 2;
    const int* src = ei;
    const int* dst = ei + E;
    const int NB = (N + BROWS - 1) >> NBSHIFT;     // 782

    char* ws = (char*)d_ws;
    size_t off = 0;
    auto alloc = [&](size_t bytes) { void* p = ws + off; off = (off + bytes + 255) & ~(size_t)255; return p; };
    int*    cursor = (int*)   alloc((size_t)MAXNB * 4);
    int2*   range  = (int2*)  alloc((size_t)N * 8);
    int*    srcs   = (int*)   alloc((size_t)NB * CAPB * 4);   // padded CSR (8.8MB)
    float*  dinv   = (float*) alloc((size_t)N * 4);
    __half* hs     = (__half*)alloc((size_t)N * DCH * 2);
    __half* agg    = (__half*)alloc((size_t)N * DCH * 2);
    unsigned int* tmp = (unsigned int*)hs;         // alias: 8.8MB tmp < 12.8MB hs; dead before gemm1
    float* out = (float*)d_out;

    const int T = 256;
    const int gAG  = (N * DCH + T - 1) / T;        // one 64-lane wave per node
    const int gGM  = (N + 63) / 64;
    const int nchk = (E + CHUNK - 1) / CHUNK;

    // ---- CSR build (counting sort by dst, fixed-capacity buckets) ----
    hipMemsetAsync(cursor, 0, (size_t)NB * 4, stream);
    bucket_scatter<<<nchk, T, 0, stream>>>(src, dst, cursor, tmp, E, NB);
    bucket_to_csr<<<NB, BROWS, 0, stream>>>(tmp, cursor, range, srcs, dinv, N);

    // ---- layer 1: x -> agg (fp16) ----
    gemm64<float><<<gGM, T, 0, stream>>>(x, W1, dinv, hs, N);
    aggregate<__half><<<gAG, T, 0, stream>>>(hs, range, srcs, dinv, b1, agg, N, 1);

    // ---- layer 2: agg -> agg ----
    gemm64<__half><<<gGM, T, 0, stream>>>(agg, W2, dinv, hs, N);
    aggregate<__half><<<gAG, T, 0, stream>>>(hs, range, srcs, dinv, b2, agg, N, 1);

    // ---- layer 3: agg -> d_out (fp32) ----
    gemm64<__half><<<gGM, T, 0, stream>>>(agg, W3, dinv, hs, N);
    aggregate<float><<<gAG, T, 0, stream>>>(hs, range, srcs, dinv, b3, out, N, 0);
}

// Round 16
// 223.613 us; speedup vs baseline: 1.5180x; 1.1017x over previous
//
#include <hip/hip_runtime.h>
#include <hip/hip_fp16.h>
#include <type_traits>

#define DCH 64
#define NBSHIFT 8
#define BROWS 256            // nodes per bucket = 1<<NBSHIFT
#define MAXNB 512
#define CAPB 5120            // fixed bucket capacity (mean 4092, +16 sigma)
#define CAP 8192             // pass-C LDS staging capacity
#define CHUNK 4096           // scatter edges per block (391 blocks)
#define SCT 512              // scatter threads

// single-pass scatter with LOCAL LDS SORT: per-chunk histogram -> scan ->
// sorted staging -> coalesced writes into per-bucket global segments.
// cursor starts zeroed (relative); segment base = b*CAPB.
__global__ __launch_bounds__(SCT) void bucket_scatter(const int* __restrict__ src,
        const int* __restrict__ dst, int* __restrict__ cursor,
        unsigned int* __restrict__ tmp, int E, int NB) {
    __shared__ int hist[MAXNB];
    __shared__ int loff[MAXNB];
    __shared__ int res[MAXNB];
    __shared__ unsigned int stage[CHUNK];
    __shared__ unsigned short stgb[CHUNK];
    const int base_e = blockIdx.x * CHUNK;
    const int nloc = min(CHUNK, E - base_e);
    const int t = threadIdx.x;
    if (t < NB) hist[t] = 0;
    __syncthreads();
    // phase 1: local ranks (static-indexed register stash)
    unsigned int pk[CHUNK / SCT];
    int bk[CHUNK / SCT], rk[CHUNK / SCT];
    #pragma unroll
    for (int c = 0; c < CHUNK / SCT; ++c) {
        int i = t + c * SCT;
        if (i < nloc) {
            int d = dst[base_e + i];
            int b = d >> NBSHIFT;
            rk[c] = atomicAdd(&hist[b], 1);
            bk[c] = b;
            pk[c] = ((unsigned int)(d & (BROWS - 1)) << 24) |
                    (unsigned int)src[base_e + i];
        }
    }
    __syncthreads();
    // scan hist -> exclusive loff; reserve global segment space
    int v = (t < NB) ? hist[t] : 0;
    loff[t] = v;
    __syncthreads();
    for (int o = 1; o < MAXNB; o <<= 1) {
        int add = (t >= o) ? loff[t - o] : 0;
        __syncthreads();
        loff[t] += add;
        __syncthreads();
    }
    int excl = loff[t] - v;
    loff[t] = excl;                       // own-slot write, no race
    if (t < NB) res[t] = v ? (t * CAPB + atomicAdd(&cursor[t], v)) : 0;
    __syncthreads();
    // place into sorted staging
    #pragma unroll
    for (int c = 0; c < CHUNK / SCT; ++c) {
        int i = t + c * SCT;
        if (i < nloc) {
            int p = loff[bk[c]] + rk[c];
            stage[p] = pk[c];
            stgb[p]  = (unsigned short)bk[c];
        }
    }
    __syncthreads();
    // coalesced write-out: consecutive i -> consecutive addresses per bucket run
    for (int i = t; i < nloc; i += SCT) {
        int b = stgb[i];
        tmp[res[b] + (i - loff[b])] = stage[i];
    }
}

// one block per bucket -> range(int2), dinv, coalesced (padded) srcs
__global__ __launch_bounds__(BROWS) void bucket_to_csr(
        const unsigned int* __restrict__ tmp, const int* __restrict__ cursor,
        int2* __restrict__ range, int* __restrict__ srcs,
        float* __restrict__ dinv, int N) {
    __shared__ int hist[BROWS];
    __shared__ int off[BROWS];
    __shared__ int cur[BROWS];
    __shared__ int stage[CAP];
    const int b = blockIdx.x;
    const int base = b * CAPB;
    const int count = cursor[b];
    const int t = threadIdx.x;
    hist[t] = 0;
    __syncthreads();
    for (int i = t; i < count; i += BROWS)
        atomicAdd(&hist[tmp[base + i] >> 24], 1);
    __syncthreads();
    int v = hist[t];
    off[t] = v;
    __syncthreads();
    for (int o = 1; o < BROWS; o <<= 1) {
        int add = (t >= o) ? off[t - o] : 0;
        __syncthreads();
        off[t] += add;
        __syncthreads();
    }
    int excl = off[t] - v;
    cur[t] = excl;
    int node = (b << NBSHIFT) + t;
    if (node < N) {
        range[node] = make_int2(base + excl, base + excl + v);
        dinv[node]  = rsqrtf((float)v + 1.0f);
    }
    __syncthreads();
    const bool st = (count <= CAP);
    for (int i = t; i < count; i += BROWS) {
        unsigned int p = tmp[base + i];
        int low = p >> 24;
        int s = (int)(p & 0xFFFFFFu);
        int pos = atomicAdd(&cur[low], 1);
        if (st) stage[pos] = s;
        else    srcs[base + pos] = s;
    }
    __syncthreads();
    if (st)
        for (int i = t; i < count; i += BROWS) srcs[base + i] = stage[i];
}

// register-tiled Hs[r][c] = half( (A*W) * dinv[r] ); 64x64 tile, 4x4/thread.
// InT = float or __half, both row-major [N][64].
template<typename InT>
__global__ __launch_bounds__(256, 4) void gemm64(const InT* __restrict__ A,
        const float* __restrict__ W, const float* __restrict__ dinv,
        __half* __restrict__ H, int nrows) {
    __shared__ float Wl[64 * 64];      // [k][c]
    __shared__ float Al[64 * 68];      // [r][k], pad 68
    #pragma unroll
    for (int j = 0; j < 4; ++j) {
        int idx = (int)threadIdx.x + j * 256;
        float4 w = ((const float4*)W)[idx];
        *(float4*)&Wl[(idx >> 4) * 64 + (idx & 15) * 4] = w;
    }
    const int tx = threadIdx.x & 15;
    const int ty = threadIdx.x >> 4;
    const int c0 = tx * 4, r0 = ty * 4;
    const int ntiles = (nrows + 63) >> 6;
    for (int tile = blockIdx.x; tile < ntiles; tile += gridDim.x) {
        const int rowbase = tile << 6;
        const int rmax = min(64, nrows - rowbase);
        __syncthreads();
        #pragma unroll
        for (int j = 0; j < 4; ++j) {
            int idx = (int)threadIdx.x + j * 256;
            int r = idx >> 4, kq = idx & 15;
            float4 a;
            if (r < rmax) {
                if constexpr (std::is_same<InT, float>::value) {
                    a = *(const float4*)(A + (size_t)(rowbase + r) * 64 + kq * 4);
                } else {
                    unsigned long long u = *(const unsigned long long*)
                        ((const __half*)A + (size_t)(rowbase + r) * 64 + kq * 4);
                    union { unsigned long long u; __half2 h[2]; } cv; cv.u = u;
                    float2 f0 = __half22float2(cv.h[0]);
                    float2 f1 = __half22float2(cv.h[1]);
                    a = make_float4(f0.x, f0.y, f1.x, f1.y);
                }
            } else a = make_float4(0.f, 0.f, 0.f, 0.f);
            *(float4*)&Al[r * 68 + kq * 4] = a;
        }
        __syncthreads();
        float acc[4][4] = {};
        #pragma unroll 8
        for (int k = 0; k < 64; ++k) {
            float4 wv = *(const float4*)&Wl[k * 64 + c0];
            float a0 = Al[(r0 + 0) * 68 + k];
            float a1 = Al[(r0 + 1) * 68 + k];
            float a2 = Al[(r0 + 2) * 68 + k];
            float a3 = Al[(r0 + 3) * 68 + k];
            acc[0][0] += a0 * wv.x; acc[0][1] += a0 * wv.y; acc[0][2] += a0 * wv.z; acc[0][3] += a0 * wv.w;
            acc[1][0] += a1 * wv.x; acc[1][1] += a1 * wv.y; acc[1][2] += a1 * wv.z; acc[1][3] += a1 * wv.w;
            acc[2][0] += a2 * wv.x; acc[2][1] += a2 * wv.y; acc[2][2] += a2 * wv.z; acc[2][3] += a2 * wv.w;
            acc[3][0] += a3 * wv.x; acc[3][1] += a3 * wv.y; acc[3][2] += a3 * wv.z; acc[3][3] += a3 * wv.w;
        }
        #pragma unroll
        for (int i = 0; i < 4; ++i) {
            int r = r0 + i;
            if (r < rmax) {
                float s = dinv[rowbase + r];
                __half2* ph = (__half2*)(H + (size_t)(rowbase + r) * 64 + c0);
                ph[0] = __floats2half2_rn(acc[i][0] * s, acc[i][1] * s);
                ph[1] = __floats2half2_rn(acc[i][2] * s, acc[i][3] * s);
            }
        }
    }
}

__device__ __forceinline__ void accumh(__half2 acc[4], float4 v) {
    const __half2* hp = (const __half2*)&v;
    #pragma unroll
    for (int j = 0; j < 4; ++j) acc[j] = __hadd2(acc[j], hp[j]);
}

__device__ __forceinline__ float4 row16(const __half* __restrict__ hs, int s, int q) {
    return *(const float4*)((const char*)hs + ((size_t)s << 7) + (q << 4));
}

// one wave per dst node (champion structure). lane = g*8+q: g = edge subgroup
// (8 edges/load-instr), q = channel oct (16B). fp16 packed accum, dual loads.
// OutT=__half: fp16 [N][64] inter-layer; OutT=float: fp32 d_out.
// out[d][c] = act( (sum_{s in N(d) ∪ {d}} hs[s][c]) * dinv[d] + b[c] )
template<typename OutT>
__global__ __launch_bounds__(256) void aggregate(
    const __half* __restrict__ hs, const int2* __restrict__ range,
    const int* __restrict__ srcs, const float* __restrict__ dinv,
    const float* __restrict__ b, OutT* __restrict__ out, int n, int do_relu)
{
    int wid  = (blockIdx.x * blockDim.x + threadIdx.x) >> 6;
    int lane = threadIdx.x & 63;
    if (wid >= n) return;
    const int g = lane >> 3;       // 0..7
    const int q = lane & 7;        // 0..7
    const int2 be = range[wid];
    const int beg = be.x, end = be.y;
    __half2 zero = __float2half2_rn(0.f);
    __half2 acch[4]  = {zero, zero, zero, zero};
    __half2 acch2[4] = {zero, zero, zero, zero};
    if (g == 7) accumh(acch, row16(hs, wid, q));    // self-loop on tail group
    int e = beg + g;
    for (; e + 8 < end; e += 16) {                  // 2 gathers in flight
        int s0 = srcs[e];
        int s1 = srcs[e + 8];
        float4 v0 = row16(hs, s0, q);
        float4 v1 = row16(hs, s1, q);
        accumh(acch, v0);
        accumh(acch2, v1);
    }
    if (e < end) accumh(acch, row16(hs, srcs[e], q));
    float acc[8];
    #pragma unroll
    for (int j = 0; j < 4; ++j) {
        float2 f0 = __half22float2(acch[j]);
        float2 f1 = __half22float2(acch2[j]);
        acc[2 * j]     = f0.x + f1.x;
        acc[2 * j + 1] = f0.y + f1.y;
    }
    #pragma unroll
    for (int j = 0; j < 8; ++j) {
        float a = acc[j];
        a += __shfl_xor(a, 8);
        a += __shfl_xor(a, 16);
        a += __shfl_xor(a, 32);
        acc[j] = a;
    }
    if (g == 0) {
        float dd = dinv[wid];
        float o[8];
        #pragma unroll
        for (int j = 0; j < 8; ++j) {
            float v = acc[j] * dd + b[q * 8 + j];
            o[j] = do_relu ? fmaxf(v, 0.f) : v;
        }
        if constexpr (std::is_same<OutT, __half>::value) {
            union { uint4 u; __half2 h[4]; } cv;
            cv.h[0] = __floats2half2_rn(o[0], o[1]);
            cv.h[1] = __floats2half2_rn(o[2], o[3]);
            cv.h[2] = __floats2half2_rn(o[4], o[5]);
            cv.h[3] = __floats2half2_rn(o[6], o[7]);
            *(uint4*)((__half*)out + (size_t)wid * DCH + q * 8) = cv.u;
        } else {
            float4* po = (float4*)((float*)out + (size_t)wid * DCH + q * 8);
            po[0] = make_float4(o[0], o[1], o[2], o[3]);
            po[1] = make_float4(o[4], o[5], o[6], o[7]);
        }
    }
}

extern "C" void kernel_launch(void* const* d_in, const int* in_sizes, int n_in,
                              void* d_out, int out_size, void* d_ws, size_t ws_size,
                              hipStream_t stream) {
    const float* x  = (const float*)d_in[0];
    const int*   ei = (const int*)d_in[1];
    const float* W1 = (const float*)d_in[2];
    const float* b1 = (const float*)d_in[3];
    const float* W2 = (const float*)d_in[4];
    const float* b2 = (const float*)d_in[5];
    const float* W3 = (const float*)d_in[6];
    const float* b3 = (const float*)d_in[7];

    const int N = in_sizes[0] / DCH;
    const int E = in_sizes[1] / 2;
    const int* src = ei;
    const int* dst = ei + E;
    const int NB = (N + BROWS - 1) >> NBSHIFT;     // 391

    char* ws = (char*)d_ws;
    size_t off = 0;
    auto alloc = [&](size_t bytes) { void* p = ws + off; off = (off + bytes + 255) & ~(size_t)255; return p; };
    int*    cursor = (int*)   alloc((size_t)MAXNB * 4);
    int2*   range  = (int2*)  alloc((size_t)N * 8);
    int*    srcs   = (int*)   alloc((size_t)NB * CAPB * 4);   // padded CSR (8MB)
    float*  dinv   = (float*) alloc((size_t)N * 4);
    __half* hs     = (__half*)alloc((size_t)N * DCH * 2);
    __half* agg    = (__half*)alloc((size_t)N * DCH * 2);
    unsigned int* tmp = (unsigned int*)hs;         // alias: 8MB tmp < 12.8MB hs; dead before gemm1
    float* out = (float*)d_out;

    const int T = 256;
    const int gAG  = (N * DCH + T - 1) / T;        // one 64-lane wave per node
    const int gGM  = (N + 63) / 64;
    const int nchk = (E + CHUNK - 1) / CHUNK;

    // ---- CSR build (counting sort by dst, fixed-capacity buckets) ----
    hipMemsetAsync(cursor, 0, (size_t)NB * 4, stream);
    bucket_scatter<<<nchk, SCT, 0, stream>>>(src, dst, cursor, tmp, E, NB);
    bucket_to_csr<<<NB, BROWS, 0, stream>>>(tmp, cursor, range, srcs, dinv, N);

    // ---- layer 1: x -> agg (fp16) ----
    gemm64<float><<<gGM, T, 0, stream>>>(x, W1, dinv, hs, N);
    aggregate<__half><<<gAG, T, 0, stream>>>(hs, range, srcs, dinv, b1, agg, N, 1);

    // ---- layer 2: agg -> agg ----
    gemm64<__half><<<gGM, T, 0, stream>>>(agg, W2, dinv, hs, N);
    aggregate<__half><<<gAG, T, 0, stream>>>(hs, range, srcs, dinv, b2, agg, N, 1);

    // ---- layer 3: agg -> d_out (fp32) ----
    gemm64<__half><<<gGM, T, 0, stream>>>(agg, W3, dinv, hs, N);
    aggregate<float><<<gAG, T, 0, stream>>>(hs, range, srcs, dinv, b3, out, N, 0);
}

// Round 17
// 202.593 us; speedup vs baseline: 1.6755x; 1.1038x over previous
//
#include <hip/hip_runtime.h>
#include <hip/hip_fp16.h>
#include <type_traits>

#define DCH 64
#define NBSHIFT 8
#define BROWS 256            // nodes per bucket = 1<<NBSHIFT
#define MAXNB 512
#define CAPB 5120            // fixed bucket capacity (mean 4092, +16 sigma)
#define CAP 8192             // pass-C LDS staging capacity
#define CHUNK 4096           // scatter edges per block (391 blocks)
#define SCT 512              // scatter threads

typedef _Float16 v8h __attribute__((ext_vector_type(8)));
typedef float    v4f __attribute__((ext_vector_type(4)));

// single-pass scatter with LOCAL LDS SORT: per-chunk histogram -> scan ->
// sorted staging -> coalesced writes into per-bucket global segments.
__global__ __launch_bounds__(SCT) void bucket_scatter(const int* __restrict__ src,
        const int* __restrict__ dst, int* __restrict__ cursor,
        unsigned int* __restrict__ tmp, int E, int NB) {
    __shared__ int hist[MAXNB];
    __shared__ int loff[MAXNB];
    __shared__ int res[MAXNB];
    __shared__ unsigned int stage[CHUNK];
    __shared__ unsigned short stgb[CHUNK];
    const int base_e = blockIdx.x * CHUNK;
    const int nloc = min(CHUNK, E - base_e);
    const int t = threadIdx.x;
    if (t < NB) hist[t] = 0;
    __syncthreads();
    unsigned int pk[CHUNK / SCT];
    int bk[CHUNK / SCT], rk[CHUNK / SCT];
    #pragma unroll
    for (int c = 0; c < CHUNK / SCT; ++c) {
        int i = t + c * SCT;
        if (i < nloc) {
            int d = dst[base_e + i];
            int b = d >> NBSHIFT;
            rk[c] = atomicAdd(&hist[b], 1);
            bk[c] = b;
            pk[c] = ((unsigned int)(d & (BROWS - 1)) << 24) |
                    (unsigned int)src[base_e + i];
        }
    }
    __syncthreads();
    int v = (t < NB) ? hist[t] : 0;
    loff[t] = v;
    __syncthreads();
    for (int o = 1; o < MAXNB; o <<= 1) {
        int add = (t >= o) ? loff[t - o] : 0;
        __syncthreads();
        loff[t] += add;
        __syncthreads();
    }
    int excl = loff[t] - v;
    loff[t] = excl;
    if (t < NB) res[t] = v ? (t * CAPB + atomicAdd(&cursor[t], v)) : 0;
    __syncthreads();
    #pragma unroll
    for (int c = 0; c < CHUNK / SCT; ++c) {
        int i = t + c * SCT;
        if (i < nloc) {
            int p = loff[bk[c]] + rk[c];
            stage[p] = pk[c];
            stgb[p]  = (unsigned short)bk[c];
        }
    }
    __syncthreads();
    for (int i = t; i < nloc; i += SCT) {
        int b = stgb[i];
        tmp[res[b] + (i - loff[b])] = stage[i];
    }
}

// one block per bucket -> range(int2), dinv, coalesced (padded) srcs
__global__ __launch_bounds__(BROWS) void bucket_to_csr(
        const unsigned int* __restrict__ tmp, const int* __restrict__ cursor,
        int2* __restrict__ range, int* __restrict__ srcs,
        float* __restrict__ dinv, int N) {
    __shared__ int hist[BROWS];
    __shared__ int off[BROWS];
    __shared__ int cur[BROWS];
    __shared__ int stage[CAP];
    const int b = blockIdx.x;
    const int base = b * CAPB;
    const int count = cursor[b];
    const int t = threadIdx.x;
    hist[t] = 0;
    __syncthreads();
    for (int i = t; i < count; i += BROWS)
        atomicAdd(&hist[tmp[base + i] >> 24], 1);
    __syncthreads();
    int v = hist[t];
    off[t] = v;
    __syncthreads();
    for (int o = 1; o < BROWS; o <<= 1) {
        int add = (t >= o) ? off[t - o] : 0;
        __syncthreads();
        off[t] += add;
        __syncthreads();
    }
    int excl = off[t] - v;
    cur[t] = excl;
    int node = (b << NBSHIFT) + t;
    if (node < N) {
        range[node] = make_int2(base + excl, base + excl + v);
        dinv[node]  = rsqrtf((float)v + 1.0f);
    }
    __syncthreads();
    const bool st = (count <= CAP);
    for (int i = t; i < count; i += BROWS) {
        unsigned int p = tmp[base + i];
        int low = p >> 24;
        int s = (int)(p & 0xFFFFFFu);
        int pos = atomicAdd(&cur[low], 1);
        if (st) stage[pos] = s;
        else    srcs[base + pos] = s;
    }
    __syncthreads();
    if (st)
        for (int i = t; i < count; i += BROWS) srcs[base + i] = stage[i];
}

// MFMA GEMM: Hs[r][c] = half( (A*W) * dinv[r] ), 64 rows/block, 4 waves.
// Each wave: 16-row band, 4 col-tiles x 2 K-steps of mfma_f32_16x16x32_f16.
// A staged fp16 [64][72] (16B-aligned rows, 2-way bank alias = free);
// W staged transposed fp16 Wt[c][72] so B-frags are contiguous 16B reads.
template<typename InT>
__global__ __launch_bounds__(256, 4) void gemm_mfma(const InT* __restrict__ A,
        const float* __restrict__ W, const float* __restrict__ dinv,
        __half* __restrict__ H, int nrows) {
    __shared__ _Float16 Wt[64 * 72];   // [c][k]
    __shared__ _Float16 Ah[64 * 72];   // [r][k]
    const int t = threadIdx.x;
    for (int i = t; i < 4096; i += 256) {
        int k = i >> 6, c = i & 63;
        Wt[c * 72 + k] = (_Float16)W[i];
    }
    const int rowbase = blockIdx.x << 6;
    const int rmax = min(64, nrows - rowbase);
    if constexpr (std::is_same<InT, float>::value) {
        #pragma unroll
        for (int j = 0; j < 4; ++j) {
            int idx = t + j * 256;          // 1024 float4s: r = idx>>4, q4 = idx&15
            int r = idx >> 4, q4 = idx & 15;
            float4 a = (r < rmax) ? *(const float4*)(A + (size_t)(rowbase + r) * 64 + q4 * 4)
                                  : make_float4(0.f, 0.f, 0.f, 0.f);
            union { uint2 u; _Float16 h[4]; } cv;
            cv.h[0] = (_Float16)a.x; cv.h[1] = (_Float16)a.y;
            cv.h[2] = (_Float16)a.z; cv.h[3] = (_Float16)a.w;
            *(uint2*)&Ah[r * 72 + q4 * 4] = cv.u;
        }
    } else {
        #pragma unroll
        for (int j = 0; j < 2; ++j) {
            int idx = t + j * 256;          // 512 uint4s: r = idx>>3, q = idx&7
            int r = idx >> 3, q = idx & 7;
            uint4 u = (r < rmax) ? *(const uint4*)((const __half*)A + (size_t)(rowbase + r) * 64 + q * 8)
                                 : make_uint4(0u, 0u, 0u, 0u);
            *(uint4*)&Ah[r * 72 + q * 8] = u;
        }
    }
    __syncthreads();
    const int w = t >> 6, lane = t & 63;
    const int m = lane & 15, kq = lane >> 4;
    const _Float16* ap = &Ah[(w * 16 + m) * 72 + kq * 8];
    v4f acc[4] = {{0.f,0.f,0.f,0.f},{0.f,0.f,0.f,0.f},{0.f,0.f,0.f,0.f},{0.f,0.f,0.f,0.f}};
    #pragma unroll
    for (int ks = 0; ks < 2; ++ks) {
        v8h a = *(const v8h*)(ap + ks * 32);
        #pragma unroll
        for (int tc = 0; tc < 4; ++tc) {
            v8h b = *(const v8h*)&Wt[(tc * 16 + m) * 72 + ks * 32 + kq * 8];
            acc[tc] = __builtin_amdgcn_mfma_f32_16x16x32_f16(a, b, acc[tc], 0, 0, 0);
        }
    }
    #pragma unroll
    for (int j = 0; j < 4; ++j) {
        int r = w * 16 + kq * 4 + j;        // C/D row = (lane>>4)*4 + reg
        if (r < rmax) {
            float s = dinv[rowbase + r];
            #pragma unroll
            for (int tc = 0; tc < 4; ++tc)
                H[(size_t)(rowbase + r) * 64 + tc * 16 + m] = __float2half(acc[tc][j] * s);
        }
    }
}

__device__ __forceinline__ void accumh(__half2 acc[4], float4 v) {
    const __half2* hp = (const __half2*)&v;
    #pragma unroll
    for (int j = 0; j < 4; ++j) acc[j] = __hadd2(acc[j], hp[j]);
}

__device__ __forceinline__ float4 row16(const __half* __restrict__ hs, int s, int q) {
    return *(const float4*)((const char*)hs + ((size_t)s << 7) + (q << 4));
}

// one wave per dst node (champion structure). lane = g*8+q. fp16 packed accum,
// dual loads. OutT=__half: fp16 [N][64] inter-layer; OutT=float: fp32 d_out.
template<typename OutT>
__global__ __launch_bounds__(256) void aggregate(
    const __half* __restrict__ hs, const int2* __restrict__ range,
    const int* __restrict__ srcs, const float* __restrict__ dinv,
    const float* __restrict__ b, OutT* __restrict__ out, int n, int do_relu)
{
    int wid  = (blockIdx.x * blockDim.x + threadIdx.x) >> 6;
    int lane = threadIdx.x & 63;
    if (wid >= n) return;
    const int g = lane >> 3;       // 0..7
    const int q = lane & 7;        // 0..7
    const int2 be = range[wid];
    const int beg = be.x, end = be.y;
    __half2 zero = __float2half2_rn(0.f);
    __half2 acch[4]  = {zero, zero, zero, zero};
    __half2 acch2[4] = {zero, zero, zero, zero};
    if (g == 7) accumh(acch, row16(hs, wid, q));    // self-loop on tail group
    int e = beg + g;
    for (; e + 8 < end; e += 16) {                  // 2 gathers in flight
        int s0 = srcs[e];
        int s1 = srcs[e + 8];
        float4 v0 = row16(hs, s0, q);
        float4 v1 = row16(hs, s1, q);
        accumh(acch, v0);
        accumh(acch2, v1);
    }
    if (e < end) accumh(acch, row16(hs, srcs[e], q));
    float acc[8];
    #pragma unroll
    for (int j = 0; j < 4; ++j) {
        float2 f0 = __half22float2(acch[j]);
        float2 f1 = __half22float2(acch2[j]);
        acc[2 * j]     = f0.x + f1.x;
        acc[2 * j + 1] = f0.y + f1.y;
    }
    #pragma unroll
    for (int j = 0; j < 8; ++j) {
        float a = acc[j];
        a += __shfl_xor(a, 8);
        a += __shfl_xor(a, 16);
        a += __shfl_xor(a, 32);
        acc[j] = a;
    }
    if (g == 0) {
        float dd = dinv[wid];
        float o[8];
        #pragma unroll
        for (int j = 0; j < 8; ++j) {
            float v = acc[j] * dd + b[q * 8 + j];
            o[j] = do_relu ? fmaxf(v, 0.f) : v;
        }
        if constexpr (std::is_same<OutT, __half>::value) {
            union { uint4 u; __half2 h[4]; } cv;
            cv.h[0] = __floats2half2_rn(o[0], o[1]);
            cv.h[1] = __floats2half2_rn(o[2], o[3]);
            cv.h[2] = __floats2half2_rn(o[4], o[5]);
            cv.h[3] = __floats2half2_rn(o[6], o[7]);
            *(uint4*)((__half*)out + (size_t)wid * DCH + q * 8) = cv.u;
        } else {
            float4* po = (float4*)((float*)out + (size_t)wid * DCH + q * 8);
            po[0] = make_float4(o[0], o[1], o[2], o[3]);
            po[1] = make_float4(o[4], o[5], o[6], o[7]);
        }
    }
}

extern "C" void kernel_launch(void* const* d_in, const int* in_sizes, int n_in,
                              void* d_out, int out_size, void* d_ws, size_t ws_size,
                              hipStream_t stream) {
    const float* x  = (const float*)d_in[0];
    const int*   ei = (const int*)d_in[1];
    const float* W1 = (const float*)d_in[2];
    const float* b1 = (const float*)d_in[3];
    const float* W2 = (const float*)d_in[4];
    const float* b2 = (const float*)d_in[5];
    const float* W3 = (const float*)d_in[6];
    const float* b3 = (const float*)d_in[7];

    const int N = in_sizes[0] / DCH;
    const int E = in_sizes[1] / 2;
    const int* src = ei;
    const int* dst = ei + E;
    const int NB = (N + BROWS - 1) >> NBSHIFT;     // 391

    char* ws = (char*)d_ws;
    size_t off = 0;
    auto alloc = [&](size_t bytes) { void* p = ws + off; off = (off + bytes + 255) & ~(size_t)255; return p; };
    int*    cursor = (int*)   alloc((size_t)MAXNB * 4);
    int2*   range  = (int2*)  alloc((size_t)N * 8);
    int*    srcs   = (int*)   alloc((size_t)NB * CAPB * 4);   // padded CSR (8MB)
    float*  dinv   = (float*) alloc((size_t)N * 4);
    __half* hs     = (__half*)alloc((size_t)N * DCH * 2);
    __half* agg    = (__half*)alloc((size_t)N * DCH * 2);
    unsigned int* tmp = (unsigned int*)hs;         // alias: 8MB tmp < 12.8MB hs; dead before gemm1
    float* out = (float*)d_out;

    const int T = 256;
    const int gAG  = (N * DCH + T - 1) / T;        // one 64-lane wave per node
    const int gGM  = (N + 63) / 64;
    const int nchk = (E + CHUNK - 1) / CHUNK;

    // ---- CSR build (counting sort by dst, fixed-capacity buckets) ----
    hipMemsetAsync(cursor, 0, (size_t)NB * 4, stream);
    bucket_scatter<<<nchk, SCT, 0, stream>>>(src, dst, cursor, tmp, E, NB);
    bucket_to_csr<<<NB, BROWS, 0, stream>>>(tmp, cursor, range, srcs, dinv, N);

    // ---- layer 1: x -> agg (fp16) ----
    gemm_mfma<float><<<gGM, T, 0, stream>>>(x, W1, dinv, hs, N);
    aggregate<__half><<<gAG, T, 0, stream>>>(hs, range, srcs, dinv, b1, agg, N, 1);

    // ---- layer 2: agg -> agg ----
    gemm_mfma<__half><<<gGM, T, 0, stream>>>(agg, W2, dinv, hs, N);
    aggregate<__half><<<gAG, T, 0, stream>>>(hs, range, srcs, dinv, b2, agg, N, 1);

    // ---- layer 3: agg -> d_out (fp32) ----
    gemm_mfma<__half><<<gGM, T, 0, stream>>>(agg, W3, dinv, hs, N);
    aggregate<float><<<gAG, T, 0, stream>>>(hs, range, srcs, dinv, b3, out, N, 0);
}